// Round 2
// baseline (4408.707 us; speedup 1.0000x reference)
//
#include <hip/hip_runtime.h>
#include <hip/hip_bf16.h>

#define DD    512
#define HH    8
#define HD    64
#define NLAYER 6
#define DFFN  2048
#define LATD  256
#define BB    4
#define LQQ   512
#define LCC   128

__device__ __forceinline__ float4 ld4(const float* p) { return *(const float4*)p; }

// ---------------------------------------------------------------------------
// Generic tiled GEMM: C[M,N] = epilogue(alpha * A @ op(B))
//   BT=true : B is [N,K] row-major (x @ W.T style)
//   BT=false: B is [K,N] row-major
// Batched via blockIdx.z -> (zb, zh) with independent strides per operand.
// Epilogue: v = alpha*acc; v += bias[n]; v += beta2*add2[m,n];
//           if act==1 v = gelu_exact(v); v += res[m,n]; C[m,n] = v
// All M,N multiples of 64; K multiple of 16 (guaranteed by problem dims).
// ---------------------------------------------------------------------------
template<bool BT>
__global__ __launch_bounds__(256)
void k_gemm(const float* __restrict__ A, long long sAb, long long sAh, int lda,
            const float* __restrict__ Bm, long long sBb, long long sBh, int ldb,
            float* __restrict__ C, long long sCb, long long sCh, int ldc,
            int K, int Hdim, float alpha,
            const float* __restrict__ bias,
            const float* __restrict__ res, int ldres,
            float beta2, const float* __restrict__ add2,
            long long s2b, long long s2h, int ld2,
            int act)
{
    const int z  = blockIdx.z;
    const int zb = z / Hdim, zh = z % Hdim;
    A  += (size_t)(zb * sAb + zh * sAh);
    Bm += (size_t)(zb * sBb + zh * sBh);
    C  += (size_t)(zb * sCb + zh * sCh);
    if (add2) add2 += (size_t)(zb * s2b + zh * s2h);

    __shared__ float As[16][68];
    __shared__ float Bs[16][68];

    const int tx = threadIdx.x, ty = threadIdx.y;
    const int t  = ty * 16 + tx;
    const int m0 = blockIdx.y * 64, n0 = blockIdx.x * 64;

    float acc[4][4];
    #pragma unroll
    for (int i = 0; i < 4; i++)
        #pragma unroll
        for (int j = 0; j < 4; j++) acc[i][j] = 0.0f;

    const int arow = t >> 2;          // 0..63
    const int akk  = (t & 3) << 2;    // 0,4,8,12

    for (int kt = 0; kt < K; kt += 16) {
        {
            float4 av = ld4(A + (size_t)(m0 + arow) * lda + (kt + akk));
            As[akk + 0][arow] = av.x; As[akk + 1][arow] = av.y;
            As[akk + 2][arow] = av.z; As[akk + 3][arow] = av.w;
        }
        if (BT) {
            float4 bv = ld4(Bm + (size_t)(n0 + arow) * ldb + (kt + akk));
            Bs[akk + 0][arow] = bv.x; Bs[akk + 1][arow] = bv.y;
            Bs[akk + 2][arow] = bv.z; Bs[akk + 3][arow] = bv.w;
        } else {
            const int kr = t >> 4;            // 0..15
            const int nn = (t & 15) << 2;     // 0..60
            float4 bv = ld4(Bm + (size_t)(kt + kr) * ldb + (n0 + nn));
            Bs[kr][nn + 0] = bv.x; Bs[kr][nn + 1] = bv.y;
            Bs[kr][nn + 2] = bv.z; Bs[kr][nn + 3] = bv.w;
        }
        __syncthreads();
        #pragma unroll
        for (int k = 0; k < 16; k++) {
            const float a0 = As[k][ty * 4 + 0], a1 = As[k][ty * 4 + 1];
            const float a2 = As[k][ty * 4 + 2], a3 = As[k][ty * 4 + 3];
            const float b0 = Bs[k][tx * 4 + 0], b1 = Bs[k][tx * 4 + 1];
            const float b2 = Bs[k][tx * 4 + 2], b3 = Bs[k][tx * 4 + 3];
            acc[0][0] += a0 * b0; acc[0][1] += a0 * b1; acc[0][2] += a0 * b2; acc[0][3] += a0 * b3;
            acc[1][0] += a1 * b0; acc[1][1] += a1 * b1; acc[1][2] += a1 * b2; acc[1][3] += a1 * b3;
            acc[2][0] += a2 * b0; acc[2][1] += a2 * b1; acc[2][2] += a2 * b2; acc[2][3] += a2 * b3;
            acc[3][0] += a3 * b0; acc[3][1] += a3 * b1; acc[3][2] += a3 * b2; acc[3][3] += a3 * b3;
        }
        __syncthreads();
    }

    #pragma unroll
    for (int i = 0; i < 4; i++) {
        const int gm = m0 + ty * 4 + i;
        #pragma unroll
        for (int j = 0; j < 4; j++) {
            const int gn = n0 + tx * 4 + j;
            float v = alpha * acc[i][j];
            if (bias) v += bias[gn];
            if (add2) v += beta2 * add2[(size_t)gm * ld2 + gn];
            if (act == 1) v = 0.5f * v * (1.0f + erff(v * 0.7071067811865475f));
            if (res)  v += res[(size_t)gm * ldres + gn];
            C[(size_t)gm * ldc + gn] = v;
        }
    }
}

// ---------------------------------------------------------------------------
// LayerNorm over last dim (512). One wave per row, 4 rows per block.
// ---------------------------------------------------------------------------
__global__ __launch_bounds__(256)
void k_ln(const float* __restrict__ X, float* __restrict__ Y,
          const float* __restrict__ g, const float* __restrict__ b)
{
    const int row  = blockIdx.x * 4 + threadIdx.y;
    const int lane = threadIdx.x;
    const float* x = X + (size_t)row * DD;
    float v[8];
    float s = 0.0f;
    #pragma unroll
    for (int i = 0; i < 8; i++) { v[i] = x[lane + i * 64]; s += v[i]; }
    #pragma unroll
    for (int off = 32; off; off >>= 1) s += __shfl_xor(s, off, 64);
    const float m = s * (1.0f / 512.0f);
    float q = 0.0f;
    #pragma unroll
    for (int i = 0; i < 8; i++) { const float d = v[i] - m; q += d * d; }
    #pragma unroll
    for (int off = 32; off; off >>= 1) q += __shfl_xor(q, off, 64);
    const float r = rsqrtf(q * (1.0f / 512.0f) + 1e-5f);
    float* y = Y + (size_t)row * DD;
    #pragma unroll
    for (int i = 0; i < 8; i++) {
        const int c = lane + i * 64;
        y[c] = (v[i] - m) * r * g[c] + b[c];
    }
}

// ---------------------------------------------------------------------------
// Row softmax, in place. One wave per row. Optional key mask (cond_mask==0).
// ---------------------------------------------------------------------------
template<int COLS>
__global__ __launch_bounds__(64)
void k_softmax(float* __restrict__ S, const float* __restrict__ mask, int rows_per_b)
{
    const int row  = blockIdx.x;
    const int lane = threadIdx.x;
    float* p = S + (size_t)row * COLS;
    const float* mrow = mask ? (mask + (size_t)(row / rows_per_b) * COLS) : nullptr;
    constexpr int NP = COLS / 64;
    float v[NP];
    float mx = -3.402823466e38f;
    #pragma unroll
    for (int i = 0; i < NP; i++) {
        const int c = lane + i * 64;
        float x = p[c];
        if (mrow && mrow[c] == 0.0f) x = -3.402823466e38f;
        v[i] = x;
        mx = fmaxf(mx, x);
    }
    #pragma unroll
    for (int off = 32; off; off >>= 1) mx = fmaxf(mx, __shfl_xor(mx, off, 64));
    float s = 0.0f;
    #pragma unroll
    for (int i = 0; i < NP; i++) { v[i] = expf(v[i] - mx); s += v[i]; }
    #pragma unroll
    for (int off = 32; off; off >>= 1) s += __shfl_xor(s, off, 64);
    const float inv = 1.0f / s;
    #pragma unroll
    for (int i = 0; i < NP; i++) p[lane + i * 64] = v[i] * inv;
}

// ---------------------------------------------------------------------------
// Sinusoidal time embedding: emb[b, 0:256]=sin(t*f_j), emb[b, 256:512]=cos
// ---------------------------------------------------------------------------
__global__ void k_emb(const int* __restrict__ t, float* __restrict__ emb)
{
    const int idx = blockIdx.x * 256 + threadIdx.x;
    if (idx >= BB * DD) return;
    const int b = idx / DD, c = idx % DD;
    const int j = (c < 256) ? c : (c - 256);
    const float freq = expf((float)j * (-9.210340371976184f / 255.0f)); // -ln(10000)/(half-1)
    const float arg = (float)t[b] * freq;
    emb[idx] = (c < 256) ? sinf(arg) : cosf(arg);
}

// Small dense layer for the time-embed path (M=B=4 rows only). act: 0 none, 2 silu
__global__ __launch_bounds__(256)
void k_small_linear(const float* __restrict__ in, int K,
                    const float* __restrict__ W, const float* __restrict__ bias,
                    float* __restrict__ out, int N, int act)
{
    const int idx = blockIdx.x * 256 + threadIdx.x;
    if (idx >= BB * N) return;
    const int b = idx / N, n = idx % N;
    const float* x = in + (size_t)b * K;
    const float* w = W + (size_t)n * K;
    float s = bias[n];
    for (int k = 0; k < K; k++) s += x[k] * w[k];
    if (act == 2) s = s / (1.0f + expf(-s));
    out[idx] = s;
}

// h[b*LQ+l, :] += tt[b, :]
__global__ void k_add_tt(float* __restrict__ h, const float* __restrict__ tt)
{
    const int idx = blockIdx.x * 256 + threadIdx.x; // over M*DD
    const int b = idx / (LQQ * DD);
    const int c = idx % DD;
    h[idx] += tt[b * DD + c];
}

// ---------------------------------------------------------------------------

extern "C" void kernel_launch(void* const* d_in, const int* in_sizes, int n_in,
                              void* d_out, int out_size, void* d_ws, size_t ws_size,
                              hipStream_t stream)
{
    const float* x_t   = (const float*)d_in[0];
    const int*   tarr  = (const int*)  d_in[1];
    const float* cond  = (const float*)d_in[2];
    const float* cmask = (const float*)d_in[3];
    const float* sa_qw = (const float*)d_in[4];
    const float* sa_kw = (const float*)d_in[5];
    const float* sa_vw = (const float*)d_in[6];
    const float* sa_ow = (const float*)d_in[7];
    const float* sa_ob = (const float*)d_in[8];
    const float* ca_qw = (const float*)d_in[9];
    const float* ca_kw = (const float*)d_in[10];
    const float* ca_vw = (const float*)d_in[11];
    const float* ca_ow = (const float*)d_in[12];
    const float* ca_ob = (const float*)d_in[13];
    const float* f1w   = (const float*)d_in[14];
    const float* f1b   = (const float*)d_in[15];
    const float* f2w   = (const float*)d_in[16];
    const float* f2b   = (const float*)d_in[17];
    const float* n1g   = (const float*)d_in[18];
    const float* n1b   = (const float*)d_in[19];
    const float* n2g   = (const float*)d_in[20];
    const float* n2b   = (const float*)d_in[21];
    const float* n3g   = (const float*)d_in[22];
    const float* n3b   = (const float*)d_in[23];
    const float* tm1w  = (const float*)d_in[24];
    const float* tm1b  = (const float*)d_in[25];
    const float* tm2w  = (const float*)d_in[26];
    const float* tm2b  = (const float*)d_in[27];
    const float* ttw   = (const float*)d_in[28];
    const float* ttb   = (const float*)d_in[29];
    const float* pinw  = (const float*)d_in[30];
    const float* pinb  = (const float*)d_in[31];
    const float* poutw = (const float*)d_in[32];
    const float* poutb = (const float*)d_in[33];
    const float* fng   = (const float*)d_in[34];
    const float* fnb   = (const float*)d_in[35];

    const int M = BB * LQQ; // 2048

    char* w8 = (char*)d_ws;
    float* h   = (float*)(w8);                          //  4 MB  [2048,512]
    float* xn  = (float*)(w8 + (size_t) 4 * 1048576);   //  4 MB
    float* qb  = (float*)(w8 + (size_t) 8 * 1048576);   //  4 MB
    float* kb  = (float*)(w8 + (size_t)12 * 1048576);   //  4 MB
    float* vb  = (float*)(w8 + (size_t)16 * 1048576);   //  4 MB
    float* ob  = (float*)(w8 + (size_t)20 * 1048576);   //  4 MB
    float* S   = (float*)(w8 + (size_t)24 * 1048576);   // 32 MB  [B,H,512,512] (aliases a1 / Sc)
    float* ub  = (float*)(w8 + (size_t)56 * 1048576);   //  4 MB  QGFD blended value buffer
    float* emb = (float*)(w8 + (size_t)60 * 1048576);
    float* h1t = emb + BB * DD;
    float* te  = h1t + BB * DFFN;
    float* ttv = te  + BB * DD;
    float* a1  = S;      // FFN hidden [2048,2048] = 16 MB, fits in S region

    const dim3 TB2(16, 16);
    const dim3 LN_B(64, 4);
    const long long ZA  = (long long)LQQ * DD;     // per-b stride in q/k/v/o (262144)
    const long long ZS  = (long long)LQQ * LQQ;    // per-head stride in S (262144)
    const long long ZC  = (long long)LQQ * LCC;    // per-head stride in Sc (65536)
    const long long ZKC = (long long)LCC * DD;     // per-b stride in cond k/v (65536)

    // ---- time embedding path ----
    k_emb<<<(BB * DD + 255) / 256, 256, 0, stream>>>(tarr, emb);
    k_small_linear<<<(BB * DFFN + 255) / 256, 256, 0, stream>>>(emb, DD, tm1w, tm1b, h1t, DFFN, 2);
    k_small_linear<<<(BB * DD + 255) / 256, 256, 0, stream>>>(h1t, DFFN, tm2w, tm2b, te, DD, 0);
    k_small_linear<<<(BB * DD + 255) / 256, 256, 0, stream>>>(te, DD, ttw, ttb, ttv, DD, 0);

    // ---- input projection: h = x_t @ pinw.T + pinb ----
    k_gemm<true><<<dim3(DD / 64, M / 64, 1), TB2, 0, stream>>>(
        x_t, 0, 0, LATD, pinw, 0, 0, LATD, h, 0, 0, DD,
        LATD, 1, 1.0f, pinb, nullptr, 0, 0.0f, nullptr, 0, 0, 0, 0);
    k_add_tt<<<(M * DD) / 256, 256, 0, stream>>>(h, ttv);

    for (int L = 0; L < NLAYER; L++) {
        const float *qw = sa_qw + (size_t)L * DD * DD, *kw = sa_kw + (size_t)L * DD * DD;
        const float *vw = sa_vw + (size_t)L * DD * DD, *ow = sa_ow + (size_t)L * DD * DD;
        const float *obv = sa_ob + (size_t)L * DD;

        // ======== self-attention with QGFD ========
        k_ln<<<M / 4, LN_B, 0, stream>>>(h, xn, n1g + (size_t)L * DD, n1b + (size_t)L * DD);

        k_gemm<true><<<dim3(DD / 64, M / 64, 1), TB2, 0, stream>>>(
            xn, 0, 0, DD, qw, 0, 0, DD, qb, 0, 0, DD,
            DD, 1, 1.0f, nullptr, nullptr, 0, 0.0f, nullptr, 0, 0, 0, 0);
        k_gemm<true><<<dim3(DD / 64, M / 64, 1), TB2, 0, stream>>>(
            xn, 0, 0, DD, kw, 0, 0, DD, kb, 0, 0, DD,
            DD, 1, 1.0f, nullptr, nullptr, 0, 0.0f, nullptr, 0, 0, 0, 0);
        k_gemm<true><<<dim3(DD / 64, M / 64, 1), TB2, 0, stream>>>(
            xn, 0, 0, DD, vw, 0, 0, DD, vb, 0, 0, DD,
            DD, 1, 1.0f, nullptr, nullptr, 0, 0.0f, nullptr, 0, 0, 0, 0);

        // scores = 0.125 * q @ k^T   [B,H,512,512]
        k_gemm<true><<<dim3(LQQ / 64, LQQ / 64, BB * HH), TB2, 0, stream>>>(
            qb, ZA, 64, DD, kb, ZA, 64, DD, S, (long long)HH * ZS, ZS, LQQ,
            HD, HH, 0.125f, nullptr, nullptr, 0, 0.0f, nullptr, 0, 0, 0, 0);
        k_softmax<LQQ><<<BB * HH * LQQ, 64, 0, stream>>>(S, (const float*)nullptr, 1);

        // QGFD via associativity: o = P @ (0.5*(P@v) + 0.5*v)
        //   ub = 0.5 * (P @ v) + 0.5 * v
        k_gemm<false><<<dim3(HD / 64, LQQ / 64, BB * HH), TB2, 0, stream>>>(
            S, (long long)HH * ZS, ZS, LQQ, vb, ZA, 64, DD, ub, ZA, 64, DD,
            LQQ, HH, 0.5f, nullptr, nullptr, 0,
            0.5f, vb, ZA, 64, DD, 0);
        //   o = P @ ub
        k_gemm<false><<<dim3(HD / 64, LQQ / 64, BB * HH), TB2, 0, stream>>>(
            S, (long long)HH * ZS, ZS, LQQ, ub, ZA, 64, DD, ob, ZA, 64, DD,
            LQQ, HH, 1.0f, nullptr, nullptr, 0, 0.0f, nullptr, 0, 0, 0, 0);

        // h += o @ ow.T + ob
        k_gemm<true><<<dim3(DD / 64, M / 64, 1), TB2, 0, stream>>>(
            ob, 0, 0, DD, ow, 0, 0, DD, h, 0, 0, DD,
            DD, 1, 1.0f, obv, h, DD, 0.0f, nullptr, 0, 0, 0, 0);

        // ======== cross-attention ========
        const float *cqw = ca_qw + (size_t)L * DD * DD, *ckw = ca_kw + (size_t)L * DD * DD;
        const float *cvw = ca_vw + (size_t)L * DD * DD, *cow = ca_ow + (size_t)L * DD * DD;
        const float *cob = ca_ob + (size_t)L * DD;

        k_ln<<<M / 4, LN_B, 0, stream>>>(h, xn, n2g + (size_t)L * DD, n2b + (size_t)L * DD);

        k_gemm<true><<<dim3(DD / 64, M / 64, 1), TB2, 0, stream>>>(
            xn, 0, 0, DD, cqw, 0, 0, DD, qb, 0, 0, DD,
            DD, 1, 1.0f, nullptr, nullptr, 0, 0.0f, nullptr, 0, 0, 0, 0);
        k_gemm<true><<<dim3(DD / 64, (BB * LCC) / 64, 1), TB2, 0, stream>>>(
            cond, 0, 0, DD, ckw, 0, 0, DD, kb, 0, 0, DD,
            DD, 1, 1.0f, nullptr, nullptr, 0, 0.0f, nullptr, 0, 0, 0, 0);
        k_gemm<true><<<dim3(DD / 64, (BB * LCC) / 64, 1), TB2, 0, stream>>>(
            cond, 0, 0, DD, cvw, 0, 0, DD, vb, 0, 0, DD,
            DD, 1, 1.0f, nullptr, nullptr, 0, 0.0f, nullptr, 0, 0, 0, 0);

        // Sc = 0.125 * q @ kc^T   [B,H,512,128]
        k_gemm<true><<<dim3(LCC / 64, LQQ / 64, BB * HH), TB2, 0, stream>>>(
            qb, ZA, 64, DD, kb, ZKC, 64, DD, S, (long long)HH * ZC, ZC, LCC,
            HD, HH, 0.125f, nullptr, nullptr, 0, 0.0f, nullptr, 0, 0, 0, 0);
        k_softmax<LCC><<<BB * HH * LQQ, 64, 0, stream>>>(S, cmask, HH * LQQ);

        // o = Sc @ vc
        k_gemm<false><<<dim3(HD / 64, LQQ / 64, BB * HH), TB2, 0, stream>>>(
            S, (long long)HH * ZC, ZC, LCC, vb, ZKC, 64, DD, ob, ZA, 64, DD,
            LCC, HH, 1.0f, nullptr, nullptr, 0, 0.0f, nullptr, 0, 0, 0, 0);

        // h += o @ cow.T + cob
        k_gemm<true><<<dim3(DD / 64, M / 64, 1), TB2, 0, stream>>>(
            ob, 0, 0, DD, cow, 0, 0, DD, h, 0, 0, DD,
            DD, 1, 1.0f, cob, h, DD, 0.0f, nullptr, 0, 0, 0, 0);

        // ======== FFN ========
        k_ln<<<M / 4, LN_B, 0, stream>>>(h, xn, n3g + (size_t)L * DD, n3b + (size_t)L * DD);

        // a1 = gelu(xn @ f1w.T + f1b)
        k_gemm<true><<<dim3(DFFN / 64, M / 64, 1), TB2, 0, stream>>>(
            xn, 0, 0, DD, f1w + (size_t)L * DFFN * DD, 0, 0, DD, a1, 0, 0, DFFN,
            DD, 1, 1.0f, f1b + (size_t)L * DFFN, nullptr, 0, 0.0f, nullptr, 0, 0, 0, 1);
        // h += a1 @ f2w.T + f2b
        k_gemm<true><<<dim3(DD / 64, M / 64, 1), TB2, 0, stream>>>(
            a1, 0, 0, DFFN, f2w + (size_t)L * DD * DFFN, 0, 0, DFFN, h, 0, 0, DD,
            DFFN, 1, 1.0f, f2b + (size_t)L * DD, h, DD, 0.0f, nullptr, 0, 0, 0, 0);
    }

    // ---- final LN + output projection (straight to d_out, fp32) ----
    k_ln<<<M / 4, LN_B, 0, stream>>>(h, xn, fng, fnb);
    k_gemm<true><<<dim3(LATD / 64, M / 64, 1), TB2, 0, stream>>>(
        xn, 0, 0, DD, poutw, 0, 0, DD, (float*)d_out, 0, 0, LATD,
        DD, 1, 1.0f, poutb, nullptr, 0, 0.0f, nullptr, 0, 0, 0, 0);
}

// Round 3
// 3288.356 us; speedup vs baseline: 1.3407x; 1.3407x over previous
//
#include <hip/hip_runtime.h>
#include <hip/hip_bf16.h>

#define DD    512
#define HH    8
#define HD    64
#define NLAYER 6
#define DFFN  2048
#define LATD  256
#define BB    4
#define LQQ   512
#define LCC   128

typedef __attribute__((ext_vector_type(8))) short bf16x8;
typedef __attribute__((ext_vector_type(4))) float f32x4;

__device__ __forceinline__ float4 ld4(const float* p) { return *(const float4*)p; }

__device__ __forceinline__ unsigned short f2bf(float f) {
    __hip_bfloat16 h = __float2bfloat16(f);
    return __builtin_bit_cast(unsigned short, h);
}

// ---------------------------------------------------------------------------
// MFMA bf16 GEMM: C[M,N] = epilogue(alpha * A @ op(B)), fp32 in, bf16 MFMA,
// fp32 accumulate, fp32 out.
//   BT=true : B is [N,K] row-major (x @ W.T style)
//   BT=false: B is [K,N] row-major
// BM=BN in {64,128}. Block = 256 threads = 4 waves (2x2), wave tile BM/2 x BN/2,
// frags of 16x16x32. LDS rows padded to 40 bf16 (80 B, 16B-aligned, <=2-way bank).
// Batched via blockIdx.z -> (zb, zh). Epilogue as before.
// ---------------------------------------------------------------------------
template<int BM, bool BT>
__global__ __launch_bounds__(256)
void k_mgemm(const float* __restrict__ A, long long sAb, long long sAh, int lda,
             const float* __restrict__ Bm, long long sBb, long long sBh, int ldb,
             float* __restrict__ C, long long sCb, long long sCh, int ldc,
             int K, int Hdim, float alpha,
             const float* __restrict__ bias,
             const float* __restrict__ res, int ldres,
             float beta2, const float* __restrict__ add2,
             long long s2b, long long s2h, int ld2,
             int act)
{
    constexpr int BN = BM;
    constexpr int SK = 40;         // padded LDS row stride in bf16 units (80 B)
    constexpr int FM = BM / 32;    // frags per wave per dim: 4 (BM=128) or 2 (BM=64)

    const int z  = blockIdx.z;
    const int zb = z / Hdim, zh = z % Hdim;
    A  += (size_t)(zb * sAb + zh * sAh);
    Bm += (size_t)(zb * sBb + zh * sBh);
    C  += (size_t)(zb * sCb + zh * sCh);
    if (add2) add2 += (size_t)(zb * s2b + zh * s2h);

    __shared__ unsigned short Asm[BM * SK];
    __shared__ unsigned short Bsm[BN * SK];

    const int t    = threadIdx.x;
    const int wid  = t >> 6, lane = t & 63;
    const int q    = lane >> 4, c = lane & 15;
    const int wm   = (wid >> 1) * (BM / 2), wn = (wid & 1) * (BN / 2);
    const int m0   = blockIdx.y * BM, n0 = blockIdx.x * BN;

    f32x4 acc[FM][FM];
    #pragma unroll
    for (int i = 0; i < FM; i++)
        #pragma unroll
        for (int j = 0; j < FM; j++) acc[i][j] = (f32x4){0.f, 0.f, 0.f, 0.f};

    for (int kt = 0; kt < K; kt += 32) {
        // ---- stage A tile [BM x 32] fp32 -> bf16 LDS [m][k] ----
        #pragma unroll
        for (int p = 0; p < BM / 32; p++) {
            const int idx = p * 256 + t;
            const int r = idx >> 3, kg = (idx & 7) << 2;
            const float4 v = ld4(A + (size_t)(m0 + r) * lda + kt + kg);
            ushort4 u;
            u.x = f2bf(v.x); u.y = f2bf(v.y); u.z = f2bf(v.z); u.w = f2bf(v.w);
            *(ushort4*)&Asm[r * SK + kg] = u;
        }
        // ---- stage B tile -> bf16 LDS [n][k] ----
        if constexpr (BT) {
            #pragma unroll
            for (int p = 0; p < BN / 32; p++) {
                const int idx = p * 256 + t;
                const int r = idx >> 3, kg = (idx & 7) << 2;
                const float4 v = ld4(Bm + (size_t)(n0 + r) * ldb + kt + kg);
                ushort4 u;
                u.x = f2bf(v.x); u.y = f2bf(v.y); u.z = f2bf(v.z); u.w = f2bf(v.w);
                *(ushort4*)&Bsm[r * SK + kg] = u;
            }
        } else {
            #pragma unroll
            for (int p = 0; p < BN / 32; p++) {
                const int idx = p * 256 + t;
                const int kk = idx / (BN / 4), ng = (idx % (BN / 4)) << 2;
                const float4 v = ld4(Bm + (size_t)(kt + kk) * ldb + n0 + ng);
                Bsm[(ng + 0) * SK + kk] = f2bf(v.x);
                Bsm[(ng + 1) * SK + kk] = f2bf(v.y);
                Bsm[(ng + 2) * SK + kk] = f2bf(v.z);
                Bsm[(ng + 3) * SK + kk] = f2bf(v.w);
            }
        }
        __syncthreads();

        bf16x8 af[FM], bf[FM];
        #pragma unroll
        for (int fm = 0; fm < FM; fm++)
            af[fm] = *(const bf16x8*)&Asm[(wm + fm * 16 + c) * SK + q * 8];
        #pragma unroll
        for (int fn = 0; fn < FM; fn++)
            bf[fn] = *(const bf16x8*)&Bsm[(wn + fn * 16 + c) * SK + q * 8];
        #pragma unroll
        for (int fm = 0; fm < FM; fm++)
            #pragma unroll
            for (int fn = 0; fn < FM; fn++)
                acc[fm][fn] = __builtin_amdgcn_mfma_f32_16x16x32_bf16(
                    af[fm], bf[fn], acc[fm][fn], 0, 0, 0);
        __syncthreads();
    }

    // ---- epilogue: C/D layout col=lane&15, row=quad*4+reg ----
    #pragma unroll
    for (int fm = 0; fm < FM; fm++) {
        #pragma unroll
        for (int reg = 0; reg < 4; reg++) {
            const int gm = m0 + wm + fm * 16 + q * 4 + reg;
            #pragma unroll
            for (int fn = 0; fn < FM; fn++) {
                const int gn = n0 + wn + fn * 16 + c;
                float v = alpha * acc[fm][fn][reg];
                if (bias) v += bias[gn];
                if (add2) v += beta2 * add2[(size_t)gm * ld2 + gn];
                if (act == 1) v = 0.5f * v * (1.0f + erff(v * 0.7071067811865475f));
                if (res)  v += res[(size_t)gm * ldres + gn];
                C[(size_t)gm * ldc + gn] = v;
            }
        }
    }
}

// ---------------------------------------------------------------------------
// LayerNorm over last dim (512). One wave per row, 4 rows per block.
// ---------------------------------------------------------------------------
__global__ __launch_bounds__(256)
void k_ln(const float* __restrict__ X, float* __restrict__ Y,
          const float* __restrict__ g, const float* __restrict__ b)
{
    const int row  = blockIdx.x * 4 + threadIdx.y;
    const int lane = threadIdx.x;
    const float* x = X + (size_t)row * DD;
    float v[8];
    float s = 0.0f;
    #pragma unroll
    for (int i = 0; i < 8; i++) { v[i] = x[lane + i * 64]; s += v[i]; }
    #pragma unroll
    for (int off = 32; off; off >>= 1) s += __shfl_xor(s, off, 64);
    const float m = s * (1.0f / 512.0f);
    float qq = 0.0f;
    #pragma unroll
    for (int i = 0; i < 8; i++) { const float d = v[i] - m; qq += d * d; }
    #pragma unroll
    for (int off = 32; off; off >>= 1) qq += __shfl_xor(qq, off, 64);
    const float r = rsqrtf(qq * (1.0f / 512.0f) + 1e-5f);
    float* y = Y + (size_t)row * DD;
    #pragma unroll
    for (int i = 0; i < 8; i++) {
        const int c = lane + i * 64;
        y[c] = (v[i] - m) * r * g[c] + b[c];
    }
}

// ---------------------------------------------------------------------------
// Row softmax, in place. One wave per row, 4 rows per block. Optional key mask.
// ---------------------------------------------------------------------------
template<int COLS>
__global__ __launch_bounds__(256)
void k_softmax(float* __restrict__ S, const float* __restrict__ mask, int rows_per_b)
{
    const int row  = blockIdx.x * 4 + threadIdx.y;
    const int lane = threadIdx.x;
    float* p = S + (size_t)row * COLS;
    const float* mrow = mask ? (mask + (size_t)(row / rows_per_b) * COLS) : nullptr;
    constexpr int NP = COLS / 64;
    float v[NP];
    float mx = -3.402823466e38f;
    #pragma unroll
    for (int i = 0; i < NP; i++) {
        const int c = lane + i * 64;
        float x = p[c];
        if (mrow && mrow[c] == 0.0f) x = -3.402823466e38f;
        v[i] = x;
        mx = fmaxf(mx, x);
    }
    #pragma unroll
    for (int off = 32; off; off >>= 1) mx = fmaxf(mx, __shfl_xor(mx, off, 64));
    float s = 0.0f;
    #pragma unroll
    for (int i = 0; i < NP; i++) { v[i] = expf(v[i] - mx); s += v[i]; }
    #pragma unroll
    for (int off = 32; off; off >>= 1) s += __shfl_xor(s, off, 64);
    const float inv = 1.0f / s;
    #pragma unroll
    for (int i = 0; i < NP; i++) p[lane + i * 64] = v[i] * inv;
}

// ---------------------------------------------------------------------------
// Sinusoidal time embedding
// ---------------------------------------------------------------------------
__global__ void k_emb(const int* __restrict__ t, float* __restrict__ emb)
{
    const int idx = blockIdx.x * 256 + threadIdx.x;
    if (idx >= BB * DD) return;
    const int b = idx / DD, c = idx % DD;
    const int j = (c < 256) ? c : (c - 256);
    const float freq = expf((float)j * (-9.210340371976184f / 255.0f));
    const float arg = (float)t[b] * freq;
    emb[idx] = (c < 256) ? sinf(arg) : cosf(arg);
}

// Wave-per-output dense layer for the tiny time-embed path (M=B=4 rows).
// Lane-strided coalesced weight reads + 64-lane shuffle reduce.
// act: 0 none, 2 silu
__global__ __launch_bounds__(256)
void k_wlin(const float* __restrict__ in, int K,
            const float* __restrict__ W, const float* __restrict__ bias,
            float* __restrict__ out, int N, int act)
{
    const int gw   = blockIdx.x * 4 + (threadIdx.x >> 6);
    const int lane = threadIdx.x & 63;
    const int b = gw / N, n = gw % N;
    const float* x = in + (size_t)b * K;
    const float* w = W + (size_t)n * K;
    float s = 0.0f;
    for (int k = lane; k < K; k += 64) s += x[k] * w[k];
    #pragma unroll
    for (int off = 32; off; off >>= 1) s += __shfl_xor(s, off, 64);
    if (lane == 0) {
        s += bias[n];
        if (act == 2) s = s / (1.0f + expf(-s));
        out[gw] = s;
    }
}

// h[b*LQ+l, :] += tt[b, :]
__global__ void k_add_tt(float* __restrict__ h, const float* __restrict__ tt)
{
    const int idx = blockIdx.x * 256 + threadIdx.x;
    const int b = idx / (LQQ * DD);
    const int c = idx % DD;
    h[idx] += tt[b * DD + c];
}

// ---------------------------------------------------------------------------

extern "C" void kernel_launch(void* const* d_in, const int* in_sizes, int n_in,
                              void* d_out, int out_size, void* d_ws, size_t ws_size,
                              hipStream_t stream)
{
    const float* x_t   = (const float*)d_in[0];
    const int*   tarr  = (const int*)  d_in[1];
    const float* cond  = (const float*)d_in[2];
    const float* cmask = (const float*)d_in[3];
    const float* sa_qw = (const float*)d_in[4];
    const float* sa_kw = (const float*)d_in[5];
    const float* sa_vw = (const float*)d_in[6];
    const float* sa_ow = (const float*)d_in[7];
    const float* sa_ob = (const float*)d_in[8];
    const float* ca_qw = (const float*)d_in[9];
    const float* ca_kw = (const float*)d_in[10];
    const float* ca_vw = (const float*)d_in[11];
    const float* ca_ow = (const float*)d_in[12];
    const float* ca_ob = (const float*)d_in[13];
    const float* f1w   = (const float*)d_in[14];
    const float* f1b   = (const float*)d_in[15];
    const float* f2w   = (const float*)d_in[16];
    const float* f2b   = (const float*)d_in[17];
    const float* n1g   = (const float*)d_in[18];
    const float* n1b   = (const float*)d_in[19];
    const float* n2g   = (const float*)d_in[20];
    const float* n2b   = (const float*)d_in[21];
    const float* n3g   = (const float*)d_in[22];
    const float* n3b   = (const float*)d_in[23];
    const float* tm1w  = (const float*)d_in[24];
    const float* tm1b  = (const float*)d_in[25];
    const float* tm2w  = (const float*)d_in[26];
    const float* tm2b  = (const float*)d_in[27];
    const float* ttw   = (const float*)d_in[28];
    const float* ttb   = (const float*)d_in[29];
    const float* pinw  = (const float*)d_in[30];
    const float* pinb  = (const float*)d_in[31];
    const float* poutw = (const float*)d_in[32];
    const float* poutb = (const float*)d_in[33];
    const float* fng   = (const float*)d_in[34];
    const float* fnb   = (const float*)d_in[35];

    const int M = BB * LQQ; // 2048

    char* w8 = (char*)d_ws;
    float* h   = (float*)(w8);                          //  4 MB  [2048,512]
    float* xn  = (float*)(w8 + (size_t) 4 * 1048576);   //  4 MB
    float* qb  = (float*)(w8 + (size_t) 8 * 1048576);   //  4 MB
    float* kb  = (float*)(w8 + (size_t)12 * 1048576);   //  4 MB
    float* vb  = (float*)(w8 + (size_t)16 * 1048576);   //  4 MB
    float* ob  = (float*)(w8 + (size_t)20 * 1048576);   //  4 MB
    float* S   = (float*)(w8 + (size_t)24 * 1048576);   // 32 MB  [B,H,512,512] (aliases a1 / Sc)
    float* ub  = (float*)(w8 + (size_t)56 * 1048576);   //  4 MB  QGFD blended value buffer
    float* emb = (float*)(w8 + (size_t)60 * 1048576);
    float* h1t = emb + BB * DD;
    float* te  = h1t + BB * DFFN;
    float* ttv = te  + BB * DD;
    float* a1  = S;      // FFN hidden [2048,2048] = 16 MB, fits in S region

    const dim3 T256(256);
    const dim3 LN_B(64, 4);
    const long long ZA  = (long long)LQQ * DD;     // 262144
    const long long ZS  = (long long)LQQ * LQQ;    // 262144
    const long long ZC  = (long long)LQQ * LCC;    // 65536
    const long long ZKC = (long long)LCC * DD;     // 65536

    // ---- time embedding path ----
    k_emb<<<(BB * DD + 255) / 256, 256, 0, stream>>>(tarr, emb);
    k_wlin<<<(BB * DFFN) / 4, T256, 0, stream>>>(emb, DD, tm1w, tm1b, h1t, DFFN, 2);
    k_wlin<<<(BB * DD) / 4,   T256, 0, stream>>>(h1t, DFFN, tm2w, tm2b, te, DD, 0);
    k_wlin<<<(BB * DD) / 4,   T256, 0, stream>>>(te, DD, ttw, ttb, ttv, DD, 0);

    // ---- input projection: h = x_t @ pinw.T + pinb ----
    k_mgemm<128, true><<<dim3(DD / 128, M / 128, 1), T256, 0, stream>>>(
        x_t, 0, 0, LATD, pinw, 0, 0, LATD, h, 0, 0, DD,
        LATD, 1, 1.0f, pinb, nullptr, 0, 0.0f, nullptr, 0, 0, 0, 0);
    k_add_tt<<<(M * DD) / 256, 256, 0, stream>>>(h, ttv);

    for (int L = 0; L < NLAYER; L++) {
        const float *qw = sa_qw + (size_t)L * DD * DD, *kw = sa_kw + (size_t)L * DD * DD;
        const float *vw = sa_vw + (size_t)L * DD * DD, *ow = sa_ow + (size_t)L * DD * DD;
        const float *obv = sa_ob + (size_t)L * DD;

        // ======== self-attention with QGFD ========
        k_ln<<<M / 4, LN_B, 0, stream>>>(h, xn, n1g + (size_t)L * DD, n1b + (size_t)L * DD);

        k_mgemm<128, true><<<dim3(DD / 128, M / 128, 1), T256, 0, stream>>>(
            xn, 0, 0, DD, qw, 0, 0, DD, qb, 0, 0, DD,
            DD, 1, 1.0f, nullptr, nullptr, 0, 0.0f, nullptr, 0, 0, 0, 0);
        k_mgemm<128, true><<<dim3(DD / 128, M / 128, 1), T256, 0, stream>>>(
            xn, 0, 0, DD, kw, 0, 0, DD, kb, 0, 0, DD,
            DD, 1, 1.0f, nullptr, nullptr, 0, 0.0f, nullptr, 0, 0, 0, 0);
        k_mgemm<128, true><<<dim3(DD / 128, M / 128, 1), T256, 0, stream>>>(
            xn, 0, 0, DD, vw, 0, 0, DD, vb, 0, 0, DD,
            DD, 1, 1.0f, nullptr, nullptr, 0, 0.0f, nullptr, 0, 0, 0, 0);

        // scores = 0.125 * q @ k^T   [B,H,512,512]
        k_mgemm<128, true><<<dim3(LQQ / 128, LQQ / 128, BB * HH), T256, 0, stream>>>(
            qb, ZA, 64, DD, kb, ZA, 64, DD, S, (long long)HH * ZS, ZS, LQQ,
            HD, HH, 0.125f, nullptr, nullptr, 0, 0.0f, nullptr, 0, 0, 0, 0);
        k_softmax<LQQ><<<(BB * HH * LQQ) / 4, LN_B, 0, stream>>>(S, (const float*)nullptr, 1);

        // QGFD via associativity: o = P @ (0.5*(P@v) + 0.5*v)
        k_mgemm<64, false><<<dim3(HD / 64, LQQ / 64, BB * HH), T256, 0, stream>>>(
            S, (long long)HH * ZS, ZS, LQQ, vb, ZA, 64, DD, ub, ZA, 64, DD,
            LQQ, HH, 0.5f, nullptr, nullptr, 0,
            0.5f, vb, ZA, 64, DD, 0);
        k_mgemm<64, false><<<dim3(HD / 64, LQQ / 64, BB * HH), T256, 0, stream>>>(
            S, (long long)HH * ZS, ZS, LQQ, ub, ZA, 64, DD, ob, ZA, 64, DD,
            LQQ, HH, 1.0f, nullptr, nullptr, 0, 0.0f, nullptr, 0, 0, 0, 0);

        // h += o @ ow.T + ob
        k_mgemm<128, true><<<dim3(DD / 128, M / 128, 1), T256, 0, stream>>>(
            ob, 0, 0, DD, ow, 0, 0, DD, h, 0, 0, DD,
            DD, 1, 1.0f, obv, h, DD, 0.0f, nullptr, 0, 0, 0, 0);

        // ======== cross-attention ========
        const float *cqw = ca_qw + (size_t)L * DD * DD, *ckw = ca_kw + (size_t)L * DD * DD;
        const float *cvw = ca_vw + (size_t)L * DD * DD, *cow = ca_ow + (size_t)L * DD * DD;
        const float *cob = ca_ob + (size_t)L * DD;

        k_ln<<<M / 4, LN_B, 0, stream>>>(h, xn, n2g + (size_t)L * DD, n2b + (size_t)L * DD);

        k_mgemm<128, true><<<dim3(DD / 128, M / 128, 1), T256, 0, stream>>>(
            xn, 0, 0, DD, cqw, 0, 0, DD, qb, 0, 0, DD,
            DD, 1, 1.0f, nullptr, nullptr, 0, 0.0f, nullptr, 0, 0, 0, 0);
        k_mgemm<64, true><<<dim3(DD / 64, (BB * LCC) / 64, 1), T256, 0, stream>>>(
            cond, 0, 0, DD, ckw, 0, 0, DD, kb, 0, 0, DD,
            DD, 1, 1.0f, nullptr, nullptr, 0, 0.0f, nullptr, 0, 0, 0, 0);
        k_mgemm<64, true><<<dim3(DD / 64, (BB * LCC) / 64, 1), T256, 0, stream>>>(
            cond, 0, 0, DD, cvw, 0, 0, DD, vb, 0, 0, DD,
            DD, 1, 1.0f, nullptr, nullptr, 0, 0.0f, nullptr, 0, 0, 0, 0);

        // Sc = 0.125 * q @ kc^T   [B,H,512,128]
        k_mgemm<64, true><<<dim3(LCC / 64, LQQ / 64, BB * HH), T256, 0, stream>>>(
            qb, ZA, 64, DD, kb, ZKC, 64, DD, S, (long long)HH * ZC, ZC, LCC,
            HD, HH, 0.125f, nullptr, nullptr, 0, 0.0f, nullptr, 0, 0, 0, 0);
        k_softmax<LCC><<<(BB * HH * LQQ) / 4, LN_B, 0, stream>>>(S, cmask, HH * LQQ);

        // o = Sc @ vc
        k_mgemm<64, false><<<dim3(HD / 64, LQQ / 64, BB * HH), T256, 0, stream>>>(
            S, (long long)HH * ZC, ZC, LCC, vb, ZKC, 64, DD, ob, ZA, 64, DD,
            LCC, HH, 1.0f, nullptr, nullptr, 0, 0.0f, nullptr, 0, 0, 0, 0);

        // h += o @ cow.T + cob
        k_mgemm<128, true><<<dim3(DD / 128, M / 128, 1), T256, 0, stream>>>(
            ob, 0, 0, DD, cow, 0, 0, DD, h, 0, 0, DD,
            DD, 1, 1.0f, cob, h, DD, 0.0f, nullptr, 0, 0, 0, 0);

        // ======== FFN ========
        k_ln<<<M / 4, LN_B, 0, stream>>>(h, xn, n3g + (size_t)L * DD, n3b + (size_t)L * DD);

        k_mgemm<128, true><<<dim3(DFFN / 128, M / 128, 1), T256, 0, stream>>>(
            xn, 0, 0, DD, f1w + (size_t)L * DFFN * DD, 0, 0, DD, a1, 0, 0, DFFN,
            DD, 1, 1.0f, f1b + (size_t)L * DFFN, nullptr, 0, 0.0f, nullptr, 0, 0, 0, 1);
        k_mgemm<128, true><<<dim3(DD / 128, M / 128, 1), T256, 0, stream>>>(
            a1, 0, 0, DFFN, f2w + (size_t)L * DD * DFFN, 0, 0, DFFN, h, 0, 0, DD,
            DFFN, 1, 1.0f, f2b + (size_t)L * DD, h, DD, 0.0f, nullptr, 0, 0, 0, 0);
    }

    // ---- final LN + output projection (straight to d_out, fp32) ----
    k_ln<<<M / 4, LN_B, 0, stream>>>(h, xn, fng, fnb);
    k_mgemm<64, true><<<dim3(LATD / 64, M / 64, 1), T256, 0, stream>>>(
        xn, 0, 0, DD, poutw, 0, 0, DD, (float*)d_out, 0, 0, LATD,
        DD, 1, 1.0f, poutb, nullptr, 0, 0.0f, nullptr, 0, 0, 0, 0);
}

// Round 4
// 1938.867 us; speedup vs baseline: 2.2739x; 1.6960x over previous
//
#include <hip/hip_runtime.h>
#include <hip/hip_bf16.h>
#include <type_traits>

#define DD    512
#define HH    8
#define HD    64
#define NLAYER 6
#define DFFN  2048
#define LATD  256
#define BB    4
#define LQQ   512
#define LCC   128

typedef unsigned short u16;
typedef __attribute__((ext_vector_type(8))) short bf16x8;
typedef __attribute__((ext_vector_type(4))) float f32x4;
typedef __attribute__((ext_vector_type(4))) unsigned short u16x4;

__device__ __forceinline__ float4 ld4(const float* p) { return *(const float4*)p; }
__device__ __forceinline__ u16 f2bf(float f) {
    __hip_bfloat16 h = __float2bfloat16(f);
    return __builtin_bit_cast(u16, h);
}
__device__ __forceinline__ float bf2f(u16 u) {
    return __uint_as_float(((unsigned int)u) << 16);
}

// ---------------------------------------------------------------------------
// MFMA bf16 GEMM, B always [N][K] row-major ("BT=true" form only).
// TA/TB in {float, u16(bf16)}; TC in {float, u16}.
// MULTI: blockIdx.z selects (B,C) pair from {1,2,3} (fused QKV / KV); else
// z = zb*Hdim+zh batches with per-operand strides.
// wt (runtime): transposed epilogue store -> C[(gm>>wt_shift)*sbT + gn*ldct +
// (gm & mask)], packing 4 consecutive-m accs into one ushort4 (bf16).
// Epilogue (normal): v=alpha*acc + bias[n]; act==1 -> exact gelu; += res.
// Epilogue (wt): v=alpha*acc + beta2*add2T (same transposed geometry).
// ---------------------------------------------------------------------------
template<int BM, typename TA, typename TB, typename TC, bool MULTI>
__global__ __launch_bounds__(256)
void k_g(const TA* __restrict__ A, long long sAb, long long sAh, int lda,
         const TB* __restrict__ B1, const TB* __restrict__ B2_, const TB* __restrict__ B3_,
         long long sBb, long long sBh, int ldb,
         TC* __restrict__ C1, TC* __restrict__ C2_, TC* __restrict__ C3_,
         long long sCb, long long sCh, int ldc,
         int K, int Hdim, float alpha,
         const float* __restrict__ bias,
         const float* __restrict__ res, int ldres,
         float beta2, const u16* __restrict__ add2, long long s2b, long long s2h,
         int act, int wt_mask, int wt_shift, long long sbT, int ldct)
{
    constexpr int BN = BM;
    constexpr int SK = 40;        // padded LDS row stride (80 B, 16B-aligned)
    constexpr int FM = BM / 32;

    const int z = blockIdx.z;
    const TB* Bm;
    TC* C;
    int wt;
    if constexpr (MULTI) {
        Bm = (z == 0) ? B1 : ((z == 1) ? B2_ : B3_);
        C  = (z == 0) ? C1 : ((z == 1) ? C2_ : C3_);
        wt = (wt_mask >> z) & 1;
    } else {
        const int zb = z / Hdim, zh = z % Hdim;
        A += (size_t)(zb * sAb + zh * sAh);
        Bm = B1 + (size_t)(zb * sBb + zh * sBh);
        C  = C1 + (size_t)(zb * sCb + zh * sCh);
        if (add2) add2 += (size_t)(zb * s2b + zh * s2h);
        wt = wt_mask & 1;
    }

    __shared__ u16 Asm[BM * SK];
    __shared__ u16 Bsm[BN * SK];

    const int t    = threadIdx.x;
    const int wid  = t >> 6, lane = t & 63;
    const int q    = lane >> 4, c = lane & 15;
    const int wm   = (wid >> 1) * (BM / 2), wn = (wid & 1) * (BN / 2);
    const int m0   = blockIdx.y * BM, n0 = blockIdx.x * BN;

    f32x4 acc[FM][FM];
    #pragma unroll
    for (int i = 0; i < FM; i++)
        #pragma unroll
        for (int j = 0; j < FM; j++) acc[i][j] = (f32x4){0.f, 0.f, 0.f, 0.f};

    for (int kt = 0; kt < K; kt += 32) {
        // ---- stage A tile [BM x 32] -> bf16 LDS [m][k] ----
        if constexpr (std::is_same<TA, float>::value) {
            #pragma unroll
            for (int p = 0; p < BM / 32; p++) {
                const int idx = p * 256 + t;
                const int r = idx >> 3, kg = (idx & 7) << 2;
                const float4 v = ld4(A + (size_t)(m0 + r) * lda + kt + kg);
                u16x4 u = { f2bf(v.x), f2bf(v.y), f2bf(v.z), f2bf(v.w) };
                *(u16x4*)&Asm[r * SK + kg] = u;
            }
        } else {
            #pragma unroll
            for (int p = 0; p < BM / 64; p++) {
                const int idx = p * 256 + t;
                const int r = idx >> 2, kg = (idx & 3) << 3;
                const uint4 raw = *(const uint4*)(A + (size_t)(m0 + r) * lda + kt + kg);
                *(uint4*)&Asm[r * SK + kg] = raw;
            }
        }
        // ---- stage B tile [BN x 32] -> bf16 LDS [n][k] ----
        if constexpr (std::is_same<TB, float>::value) {
            #pragma unroll
            for (int p = 0; p < BN / 32; p++) {
                const int idx = p * 256 + t;
                const int r = idx >> 3, kg = (idx & 7) << 2;
                const float4 v = ld4(Bm + (size_t)(n0 + r) * ldb + kt + kg);
                u16x4 u = { f2bf(v.x), f2bf(v.y), f2bf(v.z), f2bf(v.w) };
                *(u16x4*)&Bsm[r * SK + kg] = u;
            }
        } else {
            #pragma unroll
            for (int p = 0; p < BN / 64; p++) {
                const int idx = p * 256 + t;
                const int r = idx >> 2, kg = (idx & 3) << 3;
                const uint4 raw = *(const uint4*)(Bm + (size_t)(n0 + r) * ldb + kt + kg);
                *(uint4*)&Bsm[r * SK + kg] = raw;
            }
        }
        __syncthreads();

        bf16x8 af[FM], bfv[FM];
        #pragma unroll
        for (int fm = 0; fm < FM; fm++)
            af[fm] = *(const bf16x8*)&Asm[(wm + fm * 16 + c) * SK + q * 8];
        #pragma unroll
        for (int fn = 0; fn < FM; fn++)
            bfv[fn] = *(const bf16x8*)&Bsm[(wn + fn * 16 + c) * SK + q * 8];
        #pragma unroll
        for (int fm = 0; fm < FM; fm++)
            #pragma unroll
            for (int fn = 0; fn < FM; fn++)
                acc[fm][fn] = __builtin_amdgcn_mfma_f32_16x16x32_bf16(
                    af[fm], bfv[fn], acc[fm][fn], 0, 0, 0);
        __syncthreads();
    }

    // ---- epilogue: C/D frag layout col=lane&15, row=quad*4+reg ----
    if (wt) {
        if constexpr (std::is_same<TC, u16>::value) {
            #pragma unroll
            for (int fm = 0; fm < FM; fm++) {
                const int gm0 = m0 + wm + fm * 16 + q * 4;
                const long long roff =
                    (long long)(gm0 >> wt_shift) * sbT + (gm0 & ((1 << wt_shift) - 1));
                #pragma unroll
                for (int fn = 0; fn < FM; fn++) {
                    const int gn = n0 + wn + fn * 16 + c;
                    const long long a0 = (long long)gn * ldct + roff;
                    u16x4 o;
                    if (add2) {
                        const u16x4 av = *(const u16x4*)&add2[a0];
                        #pragma unroll
                        for (int r = 0; r < 4; r++)
                            o[r] = f2bf(alpha * acc[fm][fn][r] + beta2 * bf2f(av[r]));
                    } else {
                        #pragma unroll
                        for (int r = 0; r < 4; r++)
                            o[r] = f2bf(alpha * acc[fm][fn][r]);
                    }
                    *(u16x4*)&C[a0] = o;
                }
            }
        }
    } else {
        #pragma unroll
        for (int fm = 0; fm < FM; fm++) {
            #pragma unroll
            for (int reg = 0; reg < 4; reg++) {
                const int gm = m0 + wm + fm * 16 + q * 4 + reg;
                #pragma unroll
                for (int fn = 0; fn < FM; fn++) {
                    const int gn = n0 + wn + fn * 16 + c;
                    float v = alpha * acc[fm][fn][reg];
                    if (bias) v += bias[gn];
                    if (act == 1) v = 0.5f * v * (1.0f + erff(v * 0.7071067811865475f));
                    if (res)  v += res[(size_t)gm * ldres + gn];
                    if constexpr (std::is_same<TC, u16>::value)
                        C[(size_t)gm * ldc + gn] = f2bf(v);
                    else
                        C[(size_t)gm * ldc + gn] = v;
                }
            }
        }
    }
}

// ---------------------------------------------------------------------------
// LayerNorm (512): fp32 in, bf16 out. One wave per row, 4 rows/block.
// ---------------------------------------------------------------------------
__global__ __launch_bounds__(256)
void k_ln(const float* __restrict__ X, u16* __restrict__ Y,
          const float* __restrict__ g, const float* __restrict__ b)
{
    const int row  = blockIdx.x * 4 + threadIdx.y;
    const int lane = threadIdx.x;
    const float* x = X + (size_t)row * DD;
    float v[8];
    float s = 0.0f;
    #pragma unroll
    for (int i = 0; i < 8; i++) { v[i] = x[lane + i * 64]; s += v[i]; }
    #pragma unroll
    for (int off = 32; off; off >>= 1) s += __shfl_xor(s, off, 64);
    const float m = s * (1.0f / 512.0f);
    float qq = 0.0f;
    #pragma unroll
    for (int i = 0; i < 8; i++) { const float d = v[i] - m; qq += d * d; }
    #pragma unroll
    for (int off = 32; off; off >>= 1) qq += __shfl_xor(qq, off, 64);
    const float r = rsqrtf(qq * (1.0f / 512.0f) + 1e-5f);
    u16* y = Y + (size_t)row * DD;
    #pragma unroll
    for (int i = 0; i < 8; i++) {
        const int c = lane + i * 64;
        y[c] = f2bf((v[i] - m) * r * g[c] + b[c]);
    }
}

// ---------------------------------------------------------------------------
// Row softmax on bf16 scores, in place (block reads full row to regs first —
// race-free). One wave per row, 4 rows/block. Optional fp32 key mask.
// ---------------------------------------------------------------------------
template<int COLS>
__global__ __launch_bounds__(256)
void k_softmax(u16* __restrict__ S, const float* __restrict__ mask, int rows_per_b)
{
    const int row  = blockIdx.x * 4 + threadIdx.y;
    const int lane = threadIdx.x;
    u16* p = S + (size_t)row * COLS;
    const float* mrow = mask ? (mask + (size_t)(row / rows_per_b) * COLS) : nullptr;
    constexpr int NP = COLS / 64;
    float v[NP];
    float mx = -3.402823466e38f;
    #pragma unroll
    for (int i = 0; i < NP; i++) {
        const int c = lane + i * 64;
        float x = bf2f(p[c]);
        if (mrow && mrow[c] == 0.0f) x = -3.402823466e38f;
        v[i] = x;
        mx = fmaxf(mx, x);
    }
    #pragma unroll
    for (int off = 32; off; off >>= 1) mx = fmaxf(mx, __shfl_xor(mx, off, 64));
    float s = 0.0f;
    #pragma unroll
    for (int i = 0; i < NP; i++) { v[i] = expf(v[i] - mx); s += v[i]; }
    #pragma unroll
    for (int off = 32; off; off >>= 1) s += __shfl_xor(s, off, 64);
    const float inv = 1.0f / s;
    #pragma unroll
    for (int i = 0; i < NP; i++) p[lane + i * 64] = f2bf(v[i] * inv);
}

// ---------------------------------------------------------------------------
__global__ void k_emb(const int* __restrict__ t, float* __restrict__ emb)
{
    const int idx = blockIdx.x * 256 + threadIdx.x;
    if (idx >= BB * DD) return;
    const int b = idx / DD, c = idx % DD;
    const int j = (c < 256) ? c : (c - 256);
    const float freq = expf((float)j * (-9.210340371976184f / 255.0f));
    const float arg = (float)t[b] * freq;
    emb[idx] = (c < 256) ? sinf(arg) : cosf(arg);
}

// Wave-per-output dense for the tiny time-embed path. act: 0 none, 2 silu
__global__ __launch_bounds__(256)
void k_wlin(const float* __restrict__ in, int K,
            const float* __restrict__ W, const float* __restrict__ bias,
            float* __restrict__ out, int N, int act)
{
    const int gw   = blockIdx.x * 4 + (threadIdx.x >> 6);
    const int lane = threadIdx.x & 63;
    const int b = gw / N, n = gw % N;
    const float* x = in + (size_t)b * K;
    const float* w = W + (size_t)n * K;
    float s = 0.0f;
    for (int k = lane; k < K; k += 64) s += x[k] * w[k];
    #pragma unroll
    for (int off = 32; off; off >>= 1) s += __shfl_xor(s, off, 64);
    if (lane == 0) {
        s += bias[n];
        if (act == 2) s = s / (1.0f + expf(-s));
        out[gw] = s;
    }
}

__global__ void k_add_tt(float* __restrict__ h, const float* __restrict__ tt)
{
    const int idx = blockIdx.x * 256 + threadIdx.x;
    const int b = idx / (LQQ * DD);
    const int c = idx % DD;
    h[idx] += tt[b * DD + c];
}

// ---------------------------------------------------------------------------

extern "C" void kernel_launch(void* const* d_in, const int* in_sizes, int n_in,
                              void* d_out, int out_size, void* d_ws, size_t ws_size,
                              hipStream_t stream)
{
    const float* x_t   = (const float*)d_in[0];
    const int*   tarr  = (const int*)  d_in[1];
    const float* cond  = (const float*)d_in[2];
    const float* cmask = (const float*)d_in[3];
    const float* sa_qw = (const float*)d_in[4];
    const float* sa_kw = (const float*)d_in[5];
    const float* sa_vw = (const float*)d_in[6];
    const float* sa_ow = (const float*)d_in[7];
    const float* sa_ob = (const float*)d_in[8];
    const float* ca_qw = (const float*)d_in[9];
    const float* ca_kw = (const float*)d_in[10];
    const float* ca_vw = (const float*)d_in[11];
    const float* ca_ow = (const float*)d_in[12];
    const float* ca_ob = (const float*)d_in[13];
    const float* f1w   = (const float*)d_in[14];
    const float* f1b   = (const float*)d_in[15];
    const float* f2w   = (const float*)d_in[16];
    const float* f2b   = (const float*)d_in[17];
    const float* n1g   = (const float*)d_in[18];
    const float* n1b   = (const float*)d_in[19];
    const float* n2g   = (const float*)d_in[20];
    const float* n2b   = (const float*)d_in[21];
    const float* n3g   = (const float*)d_in[22];
    const float* n3b   = (const float*)d_in[23];
    const float* tm1w  = (const float*)d_in[24];
    const float* tm1b  = (const float*)d_in[25];
    const float* tm2w  = (const float*)d_in[26];
    const float* tm2b  = (const float*)d_in[27];
    const float* ttw   = (const float*)d_in[28];
    const float* ttb   = (const float*)d_in[29];
    const float* pinw  = (const float*)d_in[30];
    const float* pinb  = (const float*)d_in[31];
    const float* poutw = (const float*)d_in[32];
    const float* poutb = (const float*)d_in[33];
    const float* fng   = (const float*)d_in[34];
    const float* fnb   = (const float*)d_in[35];

    const int M = BB * LQQ; // 2048

    char* w8 = (char*)d_ws;
    float* h   = (float*)(w8);                         // [2048,512] fp32  4 MB
    u16*  xn  = (u16*)(w8 + (size_t) 4 * 1048576);     // [2048,512] bf16  2 MB
    u16*  qb  = (u16*)(w8 + (size_t) 6 * 1048576);     // 2 MB
    u16*  kb  = (u16*)(w8 + (size_t) 8 * 1048576);     // 2 MB (self K / cross K)
    u16*  vbT = (u16*)(w8 + (size_t)10 * 1048576);     // [B,H,64,512] 2 MB
    u16*  ubT = (u16*)(w8 + (size_t)12 * 1048576);     // [B,H,64,512] 2 MB
    u16*  ob  = (u16*)(w8 + (size_t)14 * 1048576);     // 2 MB
    u16*  S   = (u16*)(w8 + (size_t)16 * 1048576);     // [B,H,512,512] bf16 16 MB (also Sc)
    u16*  a1  = (u16*)(w8 + (size_t)32 * 1048576);     // [2048,2048] bf16 8 MB
    u16*  vcT = (u16*)(w8 + (size_t)40 * 1048576);     // [B,H,64,128] 0.5 MB
    float* emb = (float*)(w8 + (size_t)41 * 1048576);
    float* h1t = emb + BB * DD;
    float* te  = h1t + BB * DFFN;
    float* ttv = te  + BB * DD;

    const dim3 T256(256);
    const dim3 LN_B(64, 4);
    const long long ZA  = (long long)LQQ * DD;     // 262144  (bf16 act per-b stride)
    const long long ZS  = (long long)LQQ * LQQ;    // 262144  (S per-head)
    const long long ZC  = (long long)LQQ * LCC;    // 65536   (Sc per-head)
    const long long ZVT = (long long)HH * HD * LQQ;// 262144  (vbT/ubT per-b)
    const long long ZVH = (long long)HD * LQQ;     // 32768   (vbT/ubT per-h)
    const long long ZWT = (long long)HH * HD * LCC;// 65536   (vcT per-b)
    const long long ZWH = (long long)HD * LCC;     // 8192    (vcT per-h)

    // ---- time embedding path ----
    k_emb<<<(BB * DD + 255) / 256, 256, 0, stream>>>(tarr, emb);
    k_wlin<<<(BB * DFFN) / 4, T256, 0, stream>>>(emb, DD, tm1w, tm1b, h1t, DFFN, 2);
    k_wlin<<<(BB * DD) / 4,   T256, 0, stream>>>(h1t, DFFN, tm2w, tm2b, te, DD, 0);
    k_wlin<<<(BB * DD) / 4,   T256, 0, stream>>>(te, DD, ttw, ttb, ttv, DD, 0);

    // ---- input projection: h = x_t @ pinw.T + pinb (fp32 out) ----
    k_g<64, float, float, float, false><<<dim3(DD / 64, M / 64, 1), T256, 0, stream>>>(
        x_t, 0, 0, LATD, pinw, nullptr, nullptr, 0, 0, LATD,
        h, nullptr, nullptr, 0, 0, DD,
        LATD, 1, 1.0f, pinb, nullptr, 0, 0.0f, nullptr, 0, 0, 0, 0, 0, 0, 0);
    k_add_tt<<<(M * DD) / 256, 256, 0, stream>>>(h, ttv);

    for (int L = 0; L < NLAYER; L++) {
        const float *qw = sa_qw + (size_t)L * DD * DD, *kw = sa_kw + (size_t)L * DD * DD;
        const float *vw = sa_vw + (size_t)L * DD * DD, *ow = sa_ow + (size_t)L * DD * DD;
        const float *obv = sa_ob + (size_t)L * DD;

        // ======== self-attention with QGFD ========
        k_ln<<<M / 4, LN_B, 0, stream>>>(h, xn, n1g + (size_t)L * DD, n1b + (size_t)L * DD);

        // fused QKV (z: 0=q normal, 1=k normal, 2=v transposed write)
        k_g<64, u16, float, u16, true><<<dim3(DD / 64, M / 64, 3), T256, 0, stream>>>(
            xn, 0, 0, DD, qw, kw, vw, 0, 0, DD,
            qb, kb, vbT, 0, 0, DD,
            DD, 1, 1.0f, nullptr, nullptr, 0, 0.0f, nullptr, 0, 0, 0,
            /*wt_mask=*/4, /*wt_shift=*/9, /*sbT=*/ZVT, /*ldct=*/LQQ);

        // scores S = 0.125 * q @ k^T  (bf16 out)
        k_g<64, u16, u16, u16, false><<<dim3(LQQ / 64, LQQ / 64, BB * HH), T256, 0, stream>>>(
            qb, ZA, 64, DD, kb, nullptr, nullptr, ZA, 64, DD,
            S, nullptr, nullptr, (long long)HH * ZS, ZS, LQQ,
            HD, HH, 0.125f, nullptr, nullptr, 0, 0.0f, nullptr, 0, 0, 0, 0, 0, 0, 0);
        k_softmax<LQQ><<<(BB * HH * LQQ) / 4, LN_B, 0, stream>>>(S, nullptr, 1);

        // QGFD: ubT = (0.5*(P@v) + 0.5*v)^T  (transposed epilogue, add2 = vbT)
        k_g<64, u16, u16, u16, false><<<dim3(1, LQQ / 64, BB * HH), T256, 0, stream>>>(
            S, (long long)HH * ZS, ZS, LQQ, vbT, nullptr, nullptr, ZVT, ZVH, LQQ,
            ubT, nullptr, nullptr, ZVT, ZVH, LQQ,
            LQQ, HH, 0.5f, nullptr, nullptr, 0, 0.5f, vbT, ZVT, ZVH, 0,
            /*wt=*/1, /*shift=*/30, /*sbT=*/0, /*ldct=*/LQQ);
        // ob = P @ ub  (normal write)
        k_g<64, u16, u16, u16, false><<<dim3(1, LQQ / 64, BB * HH), T256, 0, stream>>>(
            S, (long long)HH * ZS, ZS, LQQ, ubT, nullptr, nullptr, ZVT, ZVH, LQQ,
            ob, nullptr, nullptr, ZA, 64, DD,
            LQQ, HH, 1.0f, nullptr, nullptr, 0, 0.0f, nullptr, 0, 0, 0, 0, 0, 0, 0);

        // h += ob @ ow.T + obias
        k_g<64, u16, float, float, false><<<dim3(DD / 64, M / 64, 1), T256, 0, stream>>>(
            ob, 0, 0, DD, ow, nullptr, nullptr, 0, 0, DD,
            h, nullptr, nullptr, 0, 0, DD,
            DD, 1, 1.0f, obv, h, DD, 0.0f, nullptr, 0, 0, 0, 0, 0, 0, 0);

        // ======== cross-attention ========
        const float *cqw = ca_qw + (size_t)L * DD * DD, *ckw = ca_kw + (size_t)L * DD * DD;
        const float *cvw = ca_vw + (size_t)L * DD * DD, *cow = ca_ow + (size_t)L * DD * DD;
        const float *cob = ca_ob + (size_t)L * DD;

        k_ln<<<M / 4, LN_B, 0, stream>>>(h, xn, n2g + (size_t)L * DD, n2b + (size_t)L * DD);

        k_g<64, u16, float, u16, false><<<dim3(DD / 64, M / 64, 1), T256, 0, stream>>>(
            xn, 0, 0, DD, cqw, nullptr, nullptr, 0, 0, DD,
            qb, nullptr, nullptr, 0, 0, DD,
            DD, 1, 1.0f, nullptr, nullptr, 0, 0.0f, nullptr, 0, 0, 0, 0, 0, 0, 0);

        // fused cross K/V (z: 0=k normal, 1=v transposed)
        k_g<64, float, float, u16, true><<<dim3(DD / 64, (BB * LCC) / 64, 2), T256, 0, stream>>>(
            cond, 0, 0, DD, ckw, cvw, nullptr, 0, 0, DD,
            kb, vcT, nullptr, 0, 0, DD,
            DD, 1, 1.0f, nullptr, nullptr, 0, 0.0f, nullptr, 0, 0, 0,
            /*wt_mask=*/2, /*wt_shift=*/7, /*sbT=*/ZWT, /*ldct=*/LCC);

        // Sc = 0.125 * q @ kc^T
        k_g<64, u16, u16, u16, false><<<dim3(LCC / 64, LQQ / 64, BB * HH), T256, 0, stream>>>(
            qb, ZA, 64, DD, kb, nullptr, nullptr, (long long)LCC * DD, 64, DD,
            S, nullptr, nullptr, (long long)HH * ZC, ZC, LCC,
            HD, HH, 0.125f, nullptr, nullptr, 0, 0.0f, nullptr, 0, 0, 0, 0, 0, 0, 0);
        k_softmax<LCC><<<(BB * HH * LQQ) / 4, LN_B, 0, stream>>>(S, cmask, HH * LQQ);

        // ob = Pc @ vc
        k_g<64, u16, u16, u16, false><<<dim3(1, LQQ / 64, BB * HH), T256, 0, stream>>>(
            S, (long long)HH * ZC, ZC, LCC, vcT, nullptr, nullptr, ZWT, ZWH, LCC,
            ob, nullptr, nullptr, ZA, 64, DD,
            LCC, HH, 1.0f, nullptr, nullptr, 0, 0.0f, nullptr, 0, 0, 0, 0, 0, 0, 0);

        // h += ob @ cow.T + cob
        k_g<64, u16, float, float, false><<<dim3(DD / 64, M / 64, 1), T256, 0, stream>>>(
            ob, 0, 0, DD, cow, nullptr, nullptr, 0, 0, DD,
            h, nullptr, nullptr, 0, 0, DD,
            DD, 1, 1.0f, cob, h, DD, 0.0f, nullptr, 0, 0, 0, 0, 0, 0, 0);

        // ======== FFN ========
        k_ln<<<M / 4, LN_B, 0, stream>>>(h, xn, n3g + (size_t)L * DD, n3b + (size_t)L * DD);

        // a1 = gelu(xn @ f1w.T + f1b)  bf16 out
        k_g<128, u16, float, u16, false><<<dim3(DFFN / 128, M / 128, 1), T256, 0, stream>>>(
            xn, 0, 0, DD, f1w + (size_t)L * DFFN * DD, nullptr, nullptr, 0, 0, DD,
            a1, nullptr, nullptr, 0, 0, DFFN,
            DD, 1, 1.0f, f1b + (size_t)L * DFFN, nullptr, 0, 0.0f, nullptr, 0, 0,
            /*act=*/1, 0, 0, 0, 0);
        // h += a1 @ f2w.T + f2b
        k_g<64, u16, float, float, false><<<dim3(DD / 64, M / 64, 1), T256, 0, stream>>>(
            a1, 0, 0, DFFN, f2w + (size_t)L * DD * DFFN, nullptr, nullptr, 0, 0, DFFN,
            h, nullptr, nullptr, 0, 0, DD,
            DFFN, 1, 1.0f, f2b + (size_t)L * DD, h, DD, 0.0f, nullptr, 0, 0, 0, 0, 0, 0, 0);
    }

    // ---- final LN + output projection (fp32 out to d_out) ----
    k_ln<<<M / 4, LN_B, 0, stream>>>(h, xn, fng, fnb);
    k_g<64, u16, float, float, false><<<dim3(LATD / 64, M / 64, 1), T256, 0, stream>>>(
        xn, 0, 0, DD, poutw, nullptr, nullptr, 0, 0, DD,
        (float*)d_out, nullptr, nullptr, 0, 0, LATD,
        DD, 1, 1.0f, poutb, nullptr, 0, 0.0f, nullptr, 0, 0, 0, 0, 0, 0, 0);
}